// Round 8
// baseline (6860.366 us; speedup 1.0000x reference)
//
#include <hip/hip_runtime.h>
#include <hip/hip_bf16.h>
#include <stdint.h>

// ---------------------------------------------------------------------------
// GraphEncoder. Round 8: R5 barrier-free topology (1 block = 1 batch, zero
// cross-CU sync) with 1024 threads/block (16 waves -> 2x TLP for latency
// hiding) + k-split GEMVs (half k-range per thread, LDS partial reduce) +
// depth-2 register prefetch (<=10 uint4 buffers; R6's spill was 40 buffers).
// ---------------------------------------------------------------------------

typedef __bf16 bf16_t;
typedef __bf16 bf16x8 __attribute__((ext_vector_type(8)));
typedef float  f32x4  __attribute__((ext_vector_type(4)));
typedef _Float16 f16;
typedef _Float16 f16x2 __attribute__((ext_vector_type(2)));

#define MFMA16(a,b,c) __builtin_amdgcn_mfma_f32_16x16x32_bf16((a),(b),(c),0,0,0)

// ---- workspace layout (bytes) ----
static constexpr size_t OFF_MEM   = 0;                      // f16 [1536][64][512]
static constexpr size_t OFF_WALLT = 100663296;              // u32 [64][2560][4]
static constexpr size_t OFF_WCT   = OFF_WALLT + 2621440;    // u32 [64][512][4]
static constexpr size_t OFF_WIT   = OFF_WCT + 524288;       // u32 [64][1536][4]
static constexpr size_t OFF_LEN   = OFF_WIT + 1572864;      // int [1536]
static constexpr size_t WS_NEED   = OFF_LEN + 8192;         // 105,390,080

// ---- helpers ----
__device__ __forceinline__ float dot2(unsigned w, unsigned x, float acc) {
#if __has_builtin(__builtin_amdgcn_fdot2)
  return __builtin_amdgcn_fdot2(__builtin_bit_cast(f16x2, w),
                                __builtin_bit_cast(f16x2, x), acc, false);
#else
  f16x2 wv = __builtin_bit_cast(f16x2, w);
  f16x2 xv = __builtin_bit_cast(f16x2, x);
  return acc + (float)wv[0]*(float)xv[0] + (float)wv[1]*(float)xv[1];
#endif
}
__device__ __forceinline__ unsigned pack_h2(float a, float b) {
  f16 ha = (f16)a, hb = (f16)b;
  unsigned short ua = __builtin_bit_cast(unsigned short, ha);
  unsigned short ub = __builtin_bit_cast(unsigned short, hb);
  return (unsigned)ua | ((unsigned)ub << 16);
}
__device__ __forceinline__ bf16x8 cvt8(float4 lo, float4 hi) {
  bf16x8 v;
  v[0]=(__bf16)lo.x; v[1]=(__bf16)lo.y; v[2]=(__bf16)lo.z; v[3]=(__bf16)lo.w;
  v[4]=(__bf16)hi.x; v[5]=(__bf16)hi.y; v[6]=(__bf16)hi.z; v[7]=(__bf16)hi.w;
  return v;
}
__device__ __forceinline__ float fsig(float x) {
  return __builtin_amdgcn_rcpf(1.f + __expf(-x));
}
__device__ __forceinline__ float ftanh(float x) {
  float e = __expf(-2.f * fabsf(x));
  float t = (1.f - e) * __builtin_amdgcn_rcpf(1.f + e);
  return __builtin_copysignf(t, x);
}
__device__ __forceinline__ void load_lds16(const f16* g, f16* l) {
  __builtin_amdgcn_global_load_lds(
      (const __attribute__((address_space(1))) unsigned*)g,
      (__attribute__((address_space(3))) unsigned*)l, 16, 0, 0);
}

// ======================= prep kernels (unchanged from R5) ===================
__global__ __launch_bounds__(256) void prep_w(
    const float* __restrict__ Win, const float* __restrict__ Whh,
    const float* __restrict__ Wout, const float* __restrict__ Wih,
    unsigned* __restrict__ WALLT, unsigned* __restrict__ WCT,
    unsigned* __restrict__ WIT)
{
  int t = blockIdx.x * 256 + threadIdx.x;   // 1,179,648 total u32s
  if (t < 655360) {                          // WALLT: N=2560
    int kq = t / 10240, rem = t - kq * 10240;
    int n = rem >> 2, j = rem & 3;
    int k = 8*kq + 2*j;
    float a, b;
    if (n < 512)       { a = Win[n*512 + k];        b = Win[n*512 + k + 1]; }
    else if (n < 2048) { a = Whh[(n-512)*512 + k];  b = Whh[(n-512)*512 + k + 1]; }
    else               { a = Wout[(size_t)(n-2048)*1024 + 512 + k];
                         b = Wout[(size_t)(n-2048)*1024 + 513 + k]; }
    WALLT[t] = pack_h2(a, b);
  } else if (t < 786432) {                   // WCT: N=512
    int u = t - 655360;
    int kq = u / 2048, rem = u - kq * 2048;
    int n = rem >> 2, j = rem & 3;
    int k = 8*kq + 2*j;
    WCT[u] = pack_h2(Wout[(size_t)n*1024 + k], Wout[(size_t)n*1024 + k + 1]);
  } else {                                   // WIT: N=1536
    int u = t - 786432;
    int kq = u / 6144, rem = u - kq * 6144;
    int n = rem >> 2, j = rem & 3;
    int k = 8*kq + 2*j;
    WIT[u] = pack_h2(Wih[n*512 + k], Wih[n*512 + k + 1]);
  }
}

__global__ __launch_bounds__(256) void lengths_kernel(
    const int* __restrict__ cpt, int* __restrict__ len)
{
  int r = blockIdx.x * 256 + threadIdx.x;
  if (r < 1536) {
    int c = 0;
    for (int s = 0; s < 64; ++s) c += (cpt[r*64 + s] != 0);
    len[r] = c > 1 ? c : 1;
  }
}

__global__ __launch_bounds__(256) void embed_gemm(
    const int* __restrict__ cpt, const float* __restrict__ table,
    const float* __restrict__ Weh, const float* __restrict__ beh,
    f16* __restrict__ mem)
{
  __shared__ unsigned short A_lds[64][40];
  __shared__ unsigned short B_lds[64][40];
  const int bid = blockIdx.x;
  const int M0 = (bid >> 3) * 64;
  const int N0 = (bid & 7) * 64;
  const int tid = threadIdx.x, lane = tid & 63, w = tid >> 6;
  const int l15 = lane & 15, quad = lane >> 4;
  const int srow = tid >> 2;
  const int koff = (tid & 3) * 8;
  const int tok = cpt[M0 + srow];
  const float* arow = table + (size_t)tok * 512;
  const float* brow = Weh + (size_t)(N0 + srow) * 512;

  f32x4 acc0 = {0,0,0,0}, acc1 = {0,0,0,0}, acc2 = {0,0,0,0}, acc3 = {0,0,0,0};
  for (int kt = 0; kt < 16; ++kt) {
    const int k0 = kt * 32;
    float4 alo = *(const float4*)(arow + k0 + koff);
    float4 ahi = *(const float4*)(arow + k0 + koff + 4);
    float4 blo = *(const float4*)(brow + k0 + koff);
    float4 bhi = *(const float4*)(brow + k0 + koff + 4);
    __syncthreads();
    *(bf16x8*)(&A_lds[srow][koff]) = cvt8(alo, ahi);
    *(bf16x8*)(&B_lds[srow][koff]) = cvt8(blo, bhi);
    __syncthreads();
    const int kq = quad * 8;
    bf16x8 bfr = *(const bf16x8*)(&B_lds[16*w + l15][kq]);
    bf16x8 a0 = *(const bf16x8*)(&A_lds[l15][kq]);
    bf16x8 a1 = *(const bf16x8*)(&A_lds[16 + l15][kq]);
    bf16x8 a2 = *(const bf16x8*)(&A_lds[32 + l15][kq]);
    bf16x8 a3 = *(const bf16x8*)(&A_lds[48 + l15][kq]);
    acc0 = MFMA16(a0, bfr, acc0);
    acc1 = MFMA16(a1, bfr, acc1);
    acc2 = MFMA16(a2, bfr, acc2);
    acc3 = MFMA16(a3, bfr, acc3);
  }
  const int n = N0 + 16*w + l15;
  const float bias = beh[n];
  f32x4 accs[4] = {acc0, acc1, acc2, acc3};
  #pragma unroll
  for (int mt = 0; mt < 4; ++mt) {
    #pragma unroll
    for (int r = 0; r < 4; ++r) {
      int m = M0 + mt*16 + quad*4 + r;
      float v = accs[mt][r] + bias;
      v = v > 0.f ? v : expm1f(v);
      int s = m & 63, nrow = m >> 6;
      int sent = nrow % 48, b = nrow / 48;
      mem[(((size_t)(sent*32 + b))*64 + s)*512 + n] = (f16)v;
    }
  }
}

// ======================= barrier-free per-batch scan, 1024 threads ==========
__global__ __launch_bounds__(1024, 4) void scan_local2(
    const f16* __restrict__ mem, const int* __restrict__ len,
    const unsigned* __restrict__ WALLT, const unsigned* __restrict__ WCT,
    const unsigned* __restrict__ WIT,
    const float* __restrict__ b_ih, const float* __restrict__ b_hh,
    const float* __restrict__ h0, float* __restrict__ out)
{
  __shared__ __align__(16) f16 mem_s[64][520];   // 66,560 B
  __shared__ __align__(16) float zp[2][2560];     // k-half partials (reused)
  __shared__ __align__(16) unsigned qh[256];      // q  (f16 pairs)
  __shared__ __align__(16) unsigned h2u[256];     // h  (f16 pairs)
  __shared__ __align__(16) unsigned c2u[256];     // c  (f16 pairs)
  __shared__ __align__(16) unsigned x2u[256];     // x  (f16 pairs)
  __shared__ float ghz[1536];                     // gh + b_hh
  __shared__ float hw2s[512];
  __shared__ float hf[512];
  __shared__ float sc[64], al[64];
  __shared__ float bih_s[1536], bhh_s[1536];

  const int g = blockIdx.x, tid = threadIdx.x;
  const int lane = tid & 63, wv = tid >> 6;
  const int half = tid >> 9;            // k-half: 0 or 1
  const int n0 = tid & 511;
  const int kq0 = half * 32;

  // ---- prologue: biases, h0 ----
  #pragma unroll
  for (int it = 0; it < 2; ++it) {
    int idx = tid + 1024*it;
    if (idx < 1536) { bih_s[idx] = b_ih[idx]; bhh_s[idx] = b_hh[idx]; }
  }
  if (tid < 512) hf[tid] = h0[tid];
  if (tid < 256) h2u[tid] = pack_h2(h0[2*tid], h0[2*tid + 1]);
  __syncthreads();

  for (int i = 0; i < 48; ++i) {
    // ---- (0) async-stage mem slice: 16 waves x 4 rows --------------------
    {
      const f16* src = mem + ((size_t)(i*32 + g)) * 64 * 512;
      #pragma unroll
      for (int r = 0; r < 4; ++r) {
        int s = wv*4 + r;
        load_lds16(src + (size_t)s*512 + lane*8, &mem_s[s][lane*8]);
      }
    }
    // ---- (1) S1: [W_in;W_hh;Wh2].h — 5 rows/thread, k-half, depth-2 ------
    {
      float a0=0.f, a1=0.f, a2=0.f, a3=0.f, a4=0.f;
      uint4 wb[2][5];
      #pragma unroll
      for (int j = 0; j < 5; ++j)
        wb[0][j] = *(const uint4*)(WALLT + ((size_t)kq0*2560 + n0 + 512*j)*4);
      #pragma unroll
      for (int kk = 0; kk < 32; ++kk) {
        const int cur = kk & 1, nxt = cur ^ 1;
        if (kk < 31) {
          #pragma unroll
          for (int j = 0; j < 5; ++j)
            wb[nxt][j] = *(const uint4*)(WALLT + ((size_t)(kq0+kk+1)*2560 + n0 + 512*j)*4);
        }
        uint4 h4 = *(const uint4*)(h2u + (kq0+kk)*4);
        a0 = dot2(wb[cur][0].x, h4.x, a0); a0 = dot2(wb[cur][0].y, h4.y, a0);
        a0 = dot2(wb[cur][0].z, h4.z, a0); a0 = dot2(wb[cur][0].w, h4.w, a0);
        a1 = dot2(wb[cur][1].x, h4.x, a1); a1 = dot2(wb[cur][1].y, h4.y, a1);
        a1 = dot2(wb[cur][1].z, h4.z, a1); a1 = dot2(wb[cur][1].w, h4.w, a1);
        a2 = dot2(wb[cur][2].x, h4.x, a2); a2 = dot2(wb[cur][2].y, h4.y, a2);
        a2 = dot2(wb[cur][2].z, h4.z, a2); a2 = dot2(wb[cur][2].w, h4.w, a2);
        a3 = dot2(wb[cur][3].x, h4.x, a3); a3 = dot2(wb[cur][3].y, h4.y, a3);
        a3 = dot2(wb[cur][3].z, h4.z, a3); a3 = dot2(wb[cur][3].w, h4.w, a3);
        a4 = dot2(wb[cur][4].x, h4.x, a4); a4 = dot2(wb[cur][4].y, h4.y, a4);
        a4 = dot2(wb[cur][4].z, h4.z, a4); a4 = dot2(wb[cur][4].w, h4.w, a4);
      }
      zp[half][n0]        = a0;
      zp[half][n0 + 512]  = a1;
      zp[half][n0 + 1024] = a2;
      zp[half][n0 + 1536] = a3;
      zp[half][n0 + 2048] = a4;
    }
    __syncthreads();   // zp ready; global_load_lds drained -> mem_s ready
    // combine partials: q -> qh (f16 pairs); gh -> ghz(+bhh); hw2 -> hw2s
    if (tid < 256) {
      qh[tid] = pack_h2(zp[0][2*tid] + zp[1][2*tid],
                        zp[0][2*tid+1] + zp[1][2*tid+1]);
    } else {
      int k = tid - 256;                 // 0..767 -> two ghz each
      ghz[2*k]   = zp[0][512 + 2*k]   + zp[1][512 + 2*k]   + bhh_s[2*k];
      ghz[2*k+1] = zp[0][512 + 2*k+1] + zp[1][512 + 2*k+1] + bhh_s[2*k+1];
    }
    if (tid < 512) hw2s[tid] = zp[0][2048 + tid] + zp[1][2048 + tid];
    __syncthreads();

    // ---- (2) scores: 16 threads/row --------------------------------------
    {
      const int s = tid >> 4, p = tid & 15;
      const unsigned* mrow = (const unsigned*)(&mem_s[s][0]) + p*16;
      const unsigned* qrow = qh + p*16;
      float sum = 0.f;
      #pragma unroll
      for (int k = 0; k < 16; ++k) sum = dot2(mrow[k], qrow[k], sum);
      sum += __shfl_xor(sum, 1);
      sum += __shfl_xor(sum, 2);
      sum += __shfl_xor(sum, 4);
      sum += __shfl_xor(sum, 8);
      if (p == 0) {
        int L = len[g*48 + i];
        sc[s] = (s < L) ? sum : -1e30f;
      }
    }
    __syncthreads();
    if (tid < 64) {
      float v = sc[tid];
      float mx = v;
      #pragma unroll
      for (int o = 32; o; o >>= 1) mx = fmaxf(mx, __shfl_xor(mx, o));
      float e = __expf(v - mx);
      float sm = e;
      #pragma unroll
      for (int o = 32; o; o >>= 1) sm += __shfl_xor(sm, o);
      al[tid] = e * __builtin_amdgcn_rcpf(sm);
    }
    __syncthreads();

    // ---- (3) context: s-half per thread ----------------------------------
    {
      float cacc = 0.f;
      const int sbase = half * 32;
      #pragma unroll 8
      for (int s = 0; s < 32; ++s)
        cacc += al[sbase + s] * (float)mem_s[sbase + s][n0];
      zp[half][n0] = cacc;
    }
    __syncthreads();
    if (tid < 256)
      c2u[tid] = pack_h2(zp[0][2*tid] + zp[1][2*tid],
                         zp[0][2*tid+1] + zp[1][2*tid+1]);
    __syncthreads();

    // ---- (4) x = tanh(c.WC + hw2): 1 row/thread, k-half, depth-2 ---------
    {
      float acc = 0.f;
      uint4 wb[2];
      wb[0] = *(const uint4*)(WCT + ((size_t)kq0*512 + n0)*4);
      #pragma unroll
      for (int kk = 0; kk < 32; ++kk) {
        const int cur = kk & 1;
        if (kk < 31)
          wb[cur^1] = *(const uint4*)(WCT + ((size_t)(kq0+kk+1)*512 + n0)*4);
        uint4 c4 = *(const uint4*)(c2u + (kq0+kk)*4);
        acc = dot2(wb[cur].x, c4.x, acc); acc = dot2(wb[cur].y, c4.y, acc);
        acc = dot2(wb[cur].z, c4.z, acc); acc = dot2(wb[cur].w, c4.w, acc);
      }
      zp[half][n0] = acc;
    }
    __syncthreads();
    if (tid < 512) {
      float xv = ftanh(zp[0][tid] + zp[1][tid] + hw2s[tid]);
      float xp = __shfl_down(xv, 1);
      if ((tid & 1) == 0) x2u[tid >> 1] = pack_h2(xv, xp);
    }
    __syncthreads();

    // ---- (5) gi = x.W_ih^T: 3 rows/thread, k-half, depth-2 ---------------
    {
      float a0 = 0.f, a1 = 0.f, a2 = 0.f;
      uint4 wb[2][3];
      #pragma unroll
      for (int j = 0; j < 3; ++j)
        wb[0][j] = *(const uint4*)(WIT + ((size_t)kq0*1536 + n0 + 512*j)*4);
      #pragma unroll
      for (int kk = 0; kk < 32; ++kk) {
        const int cur = kk & 1, nxt = cur ^ 1;
        if (kk < 31) {
          #pragma unroll
          for (int j = 0; j < 3; ++j)
            wb[nxt][j] = *(const uint4*)(WIT + ((size_t)(kq0+kk+1)*1536 + n0 + 512*j)*4);
        }
        uint4 x4 = *(const uint4*)(x2u + (kq0+kk)*4);
        a0 = dot2(wb[cur][0].x, x4.x, a0); a0 = dot2(wb[cur][0].y, x4.y, a0);
        a0 = dot2(wb[cur][0].z, x4.z, a0); a0 = dot2(wb[cur][0].w, x4.w, a0);
        a1 = dot2(wb[cur][1].x, x4.x, a1); a1 = dot2(wb[cur][1].y, x4.y, a1);
        a1 = dot2(wb[cur][1].z, x4.z, a1); a1 = dot2(wb[cur][1].w, x4.w, a1);
        a2 = dot2(wb[cur][2].x, x4.x, a2); a2 = dot2(wb[cur][2].y, x4.y, a2);
        a2 = dot2(wb[cur][2].z, x4.z, a2); a2 = dot2(wb[cur][2].w, x4.w, a2);
      }
      zp[half][n0]        = a0;
      zp[half][n0 + 512]  = a1;
      zp[half][n0 + 1024] = a2;
    }
    __syncthreads();

    // ---- (6) GRU update ---------------------------------------------------
    if (tid < 512) {
      const int d = tid;
      float ir = zp[0][d]        + zp[1][d]        + bih_s[d];
      float iz = zp[0][512 + d]  + zp[1][512 + d]  + bih_s[512 + d];
      float in = zp[0][1024 + d] + zp[1][1024 + d] + bih_s[1024 + d];
      float hr = ghz[d], hz = ghz[512 + d], hn = ghz[1024 + d];
      float ho = hf[d];
      float rr = fsig(ir + hr);
      float zz = fsig(iz + hz);
      float nn = ftanh(in + rr * hn);
      float res = (1.f - zz) * nn + zz * ho;
      if (i == 47) {
        out[g*512 + d] = res;
      } else {
        hf[d] = res;
        float rp = __shfl_down(res, 1);
        if ((d & 1) == 0) h2u[d >> 1] = pack_h2(res, rp);
      }
    }
    __syncthreads();
  }
}

// ---------------------------------------------------------------------------
extern "C" void kernel_launch(void* const* d_in, const int* in_sizes, int n_in,
                              void* d_out, int out_size, void* d_ws, size_t ws_size,
                              hipStream_t stream) {
  const int*   cpt   = (const int*)d_in[0];
  const float* table = (const float*)d_in[2];
  const float* Weh   = (const float*)d_in[3];
  const float* beh   = (const float*)d_in[4];
  const float* h0    = (const float*)d_in[5];
  const float* Win   = (const float*)d_in[6];
  const float* Wout  = (const float*)d_in[7];
  const float* Wih   = (const float*)d_in[8];
  const float* Whh   = (const float*)d_in[9];
  const float* bih   = (const float*)d_in[10];
  const float* bhh   = (const float*)d_in[11];

  if (ws_size < WS_NEED) return;

  char* ws = (char*)d_ws;
  f16*      mem   = (f16*)(ws + OFF_MEM);
  unsigned* WALLT = (unsigned*)(ws + OFF_WALLT);
  unsigned* WCT   = (unsigned*)(ws + OFF_WCT);
  unsigned* WIT   = (unsigned*)(ws + OFF_WIT);
  int*      len   = (int*)(ws + OFF_LEN);

  prep_w<<<4608, 256, 0, stream>>>(Win, Whh, Wout, Wih, WALLT, WCT, WIT);
  lengths_kernel<<<6, 256, 0, stream>>>(cpt, len);
  embed_gemm<<<12288, 256, 0, stream>>>(cpt, table, Weh, beh, mem);
  scan_local2<<<32, 1024, 0, stream>>>(mem, len, WALLT, WCT, WIT,
                                       bih, bhh, h0, (float*)d_out);
}